// Round 12
// baseline (173.748 us; speedup 1.0000x reference)
//
#include <hip/hip_runtime.h>
#include <math.h>

#define NN 20000     // nodes
#define NE 320000    // edges
#define NR 500       // relations
#define EMBD 256
#define D4 64
#define BQ 32        // batch
#define TOT (2 * NN) // bins (in | out)
#define NB 40        // scan blocks (40*1024 >= TOT)

#define NPART 4          // XCD-class partitions (xcc & 3)
#define SEG (2 * NE)     // over-provisioned per-part segment (uints)
#define XCC_HWREG 6164   // s_getreg imm: id=20 (XCC_ID), offset=0, size=4  [m09]

#define NBLK_HIST 1250           // (NE+255)/256
#define NBLK_BN 448              // weight-pack blocks
#define NBLK_K1 (NBLK_HIST + NBLK_BN + 2 + BQ)

#define NBLK_GC1 939             // 313*3 C1-GEMM blocks
#define NBLK_GE1 32              // 8*4 E1-GEMM blocks
#define NBLK_MEGA (NBLK_HIST + NBLK_GC1 + NBLK_GE1)

typedef __attribute__((ext_vector_type(8))) short bf16x8;
typedef __attribute__((ext_vector_type(4))) float f32x4;

__device__ __forceinline__ unsigned short f2bf(float x)
{
    unsigned int u = __float_as_uint(x);
    unsigned int r = (u + 0x7fffu + ((u >> 16) & 1u)) >> 16;   // RNE
    return (unsigned short)r;
}

__device__ __forceinline__ float4 bf4tof4(uint2 u)
{
    float4 r;
    r.x = __uint_as_float((u.x & 0xFFFFu) << 16);
    r.y = __uint_as_float(u.x & 0xFFFF0000u);
    r.z = __uint_as_float((u.y & 0xFFFFu) << 16);
    r.w = __uint_as_float(u.y & 0xFFFF0000u);
    return r;
}

// ---------------- K1: hist | weight pack | params | rels-MLP ----------------
__global__ __launch_bounds__(256) void k_prep(
    const int* __restrict__ src, const int* __restrict__ dst, int* __restrict__ cnt,
    const float* __restrict__ W_O1, const float* __restrict__ W_I1,
    const float* __restrict__ W_S1, const float* __restrict__ Wr1,
    const float* __restrict__ W_O2, const float* __restrict__ W_I2,
    const float* __restrict__ W_S2,
    unsigned short* __restrict__ Bn1, unsigned short* __restrict__ Bn2,
    const float* __restrict__ bO1, const float* __restrict__ bI1,
    const float* __restrict__ bS1,
    const float* __restrict__ g1, const float* __restrict__ bb1,
    const float* __restrict__ m1, const float* __restrict__ v1,
    const float* __restrict__ bO2, const float* __restrict__ bI2,
    const float* __restrict__ bS2,
    const float* __restrict__ g2, const float* __restrict__ bb2,
    const float* __restrict__ m2, const float* __restrict__ v2,
    float* __restrict__ s1, float* __restrict__ t1,
    float* __restrict__ s2, float* __restrict__ t2,
    const float* __restrict__ edge_embs,
    const float* __restrict__ br1, const float* __restrict__ br2,
    const float* __restrict__ Wr2full, const int* __restrict__ rids,
    float* __restrict__ rels)
{
    int b = blockIdx.x;
    if (b < NBLK_HIST) {
        int i = b * 256 + threadIdx.x;
        if (i < NE) {
            atomicAdd(&cnt[dst[i]], 1);
            atomicAdd(&cnt[NN + src[i]], 1);
        }
        return;
    }
    b -= NBLK_HIST;
    if (b < NBLK_BN) {
        int id = b * 256 + threadIdx.x;
        if (id < 256 * 256) {
            int n = id >> 8, k = id & 255;
            float v;
            if (n < 64)       v = W_O1[n * 256 + k];
            else if (n < 128) v = W_I1[(n - 64) * 256 + k];
            else if (n < 192) v = W_S1[(n - 128) * 256 + k];
            else              v = Wr1[(n - 192) * 256 + k];
            Bn1[id] = f2bf(v);
        } else {
            int id2 = id - 256 * 256;
            if (id2 < 256 * 192) {
                int n = id2 / 192, k = id2 - n * 192;
                float v;
                if (k < 64)       v = W_O2[n * 64 + k];
                else if (k < 128) v = W_I2[n * 64 + (k - 64)];
                else              v = W_S2[n * 64 + (k - 128)];
                Bn2[id2] = f2bf(v);
            }
        }
        return;
    }
    b -= NBLK_BN;
    if (b < 2) {
        int i = b * 256 + threadIdx.x;   // [0,512)
        if (i < 64) {
            float rsg = g1[i] / sqrtf(v1[i] + 1e-5f);
            s1[i] = rsg * (1.f / 3.f);
            t1[i] = ((bO1[i] + bI1[i] + bS1[i]) * (1.f / 3.f) - m1[i]) * rsg + bb1[i];
        } else if (i < 320) {
            int n = i - 64;
            float rsg = g2[n] / sqrtf(v2[n] + 1e-5f);
            s2[n] = rsg * (1.f / 3.f);
            t2[n] = ((bO2[n] + bI2[n] + bS2[n]) * (1.f / 3.f) - m2[n]) * rsg + bb2[n];
        }
        return;
    }
    // rels MLP
    {
        __shared__ float e_s[256];
        __shared__ float m_s[64];
        int rb = b - 2, o = threadIdx.x;
        int rid = rids[rb];
        e_s[o] = edge_embs[(size_t)rid * 256 + o];
        __syncthreads();
        if (o < 64) {
            float acc = br1[o];
            for (int k = 0; k < 256; ++k) acc = fmaf(e_s[k], Wr1[o * 256 + k], acc);
            m_s[o] = fmaxf(acc, 0.f);
        }
        __syncthreads();
        float r = br2[o];
        for (int jj = 0; jj < 64; ++jj) r = fmaf(m_s[jj], Wr2full[o * 64 + jj], r);
        rels[rb * 256 + o] = r;
    }
}

// ---------------- scan pipeline (40K bins) ----------------

__global__ __launch_bounds__(256) void k_scanA(const int* __restrict__ cnt,
                                               int* __restrict__ bsum)
{
    __shared__ int lds[256];
    int t = threadIdx.x;
    int base = blockIdx.x * 1024 + t * 4;
    int s = 0;
    if (base + 3 < TOT) {
        int4 v = *(const int4*)(cnt + base);
        s = v.x + v.y + v.z + v.w;
    } else {
        for (int c = 0; c < 4; ++c) { int i = base + c; if (i < TOT) s += cnt[i]; }
    }
    lds[t] = s;
    __syncthreads();
    for (int d = 128; d > 0; d >>= 1) {
        if (t < d) lds[t] += lds[t + d];
        __syncthreads();
    }
    if (t == 0) bsum[blockIdx.x] = lds[0];
}

__global__ __launch_bounds__(64) void k_scanB(int* __restrict__ bsum)
{
    int t = threadIdx.x;
    int v = (t < NB) ? bsum[t] : 0;
#pragma unroll
    for (int d = 1; d < 64; d <<= 1) {
        int u = __shfl_up(v, d, 64);
        if (t >= d) v += u;
    }
    int ex = __shfl_up(v, 1, 64);
    if (t == 0) ex = 0;
    if (t < NB) bsum[t] = ex;
}

__global__ __launch_bounds__(256) void k_scanC(const int* __restrict__ cnt,
                                               const int* __restrict__ bsum,
                                               int* __restrict__ off_bin)
{
    __shared__ int lds[256];
    int t = threadIdx.x;
    int base = blockIdx.x * 1024 + t * 4;
    int e0 = 0, e1 = 0, e2 = 0, e3 = 0;
    if (base + 3 < TOT) {
        int4 v = *(const int4*)(cnt + base);
        e0 = v.x; e1 = v.y; e2 = v.z; e3 = v.w;
    } else {
        if (base + 0 < TOT) e0 = cnt[base + 0];
        if (base + 1 < TOT) e1 = cnt[base + 1];
        if (base + 2 < TOT) e2 = cnt[base + 2];
        if (base + 3 < TOT) e3 = cnt[base + 3];
    }
    int s = e0 + e1 + e2 + e3;
    lds[t] = s;
    __syncthreads();
    for (int d = 1; d < 256; d <<= 1) {
        int u = (t >= d) ? lds[t - d] : 0;
        __syncthreads();
        lds[t] += u;
        __syncthreads();
    }
    int run = lds[t] - s + bsum[blockIdx.x];
    if (base + 3 < TOT) {
        int4 o = make_int4(run, run + e0, run + e0 + e1, run + e0 + e1 + e2);
        *(int4*)(off_bin + base) = o;
    } else {
        int r = run;
        if (base + 0 < TOT) { off_bin[base + 0] = r; r += e0; }
        if (base + 1 < TOT) { off_bin[base + 1] = r; r += e1; }
        if (base + 2 < TOT) { off_bin[base + 2] = r; r += e2; }
        if (base + 3 < TOT) { off_bin[base + 3] = r; r += e3; }
    }
    if (blockIdx.x == 0 && t == 0) off_bin[TOT] = 2 * NE;
}

// ---------------- MFMA bf16 GEMM body ----------------
__device__ __forceinline__ void gemm_dev(
    unsigned short* As, unsigned short* Bs,
    const void* __restrict__ Av, int aBf16, int M, int K, int lda,
    const unsigned short* __restrict__ Bn,
    void* __restrict__ C, int ldc, int mode,
    const float* __restrict__ sv, const float* __restrict__ tv,
    const float* __restrict__ node_embs, const int* __restrict__ flag,
    int m0, int n0)
{
    const int t = threadIdx.x;
    const int lane = t & 63, wave = t >> 6;
    const int wr = wave >> 1, wc = wave & 1;
    const int lrow = lane & 15, lkg = lane >> 4;

    f32x4 acc[2][2] = {};

    for (int kb = 0; kb < K; kb += 64) {
        if (aBf16) {
            const unsigned short* A = (const unsigned short*)Av;
#pragma unroll
            for (int it = 0; it < 2; ++it) {
                int idx = t + it * 256;
                int ko = idx & 7;
                int row = idx >> 3;
                int gm = m0 + row;
                uint4 a = make_uint4(0u, 0u, 0u, 0u);
                if (gm < M) a = *(const uint4*)(A + (size_t)gm * lda + kb + 8 * ko);
                *(uint4*)&As[row * 72 + 8 * ko] = a;
            }
        } else {
            const float* A = (const float*)Av;
#pragma unroll
            for (int it = 0; it < 4; ++it) {
                int idx = t + it * 256;
                int kq = idx & 15;
                int row = idx >> 4;
                int gm = m0 + row;
                float4 a = make_float4(0.f, 0.f, 0.f, 0.f);
                if (gm < M) a = *(const float4*)(A + (size_t)gm * lda + kb + 4 * kq);
                unsigned int p0 = (unsigned int)f2bf(a.x) | ((unsigned int)f2bf(a.y) << 16);
                unsigned int p1 = (unsigned int)f2bf(a.z) | ((unsigned int)f2bf(a.w) << 16);
                *(uint2*)&As[row * 72 + 4 * kq] = make_uint2(p0, p1);
            }
        }
#pragma unroll
        for (int it = 0; it < 2; ++it) {
            int idx = t + it * 256;
            int ko = idx & 7;
            int row = idx >> 3;
            uint4 b = *(const uint4*)(Bn + (size_t)(n0 + row) * K + kb + 8 * ko);
            *(uint4*)&Bs[row * 72 + 8 * ko] = b;
        }
        __syncthreads();
#pragma unroll
        for (int ks = 0; ks < 2; ++ks) {
            int k0 = ks * 32 + lkg * 8;
            bf16x8 af0 = *(const bf16x8*)&As[(wr * 32 + lrow) * 72 + k0];
            bf16x8 af1 = *(const bf16x8*)&As[(wr * 32 + 16 + lrow) * 72 + k0];
            bf16x8 bf0 = *(const bf16x8*)&Bs[(wc * 32 + lrow) * 72 + k0];
            bf16x8 bf1 = *(const bf16x8*)&Bs[(wc * 32 + 16 + lrow) * 72 + k0];
            acc[0][0] = __builtin_amdgcn_mfma_f32_16x16x32_bf16(af0, bf0, acc[0][0], 0, 0, 0);
            acc[0][1] = __builtin_amdgcn_mfma_f32_16x16x32_bf16(af0, bf1, acc[0][1], 0, 0, 0);
            acc[1][0] = __builtin_amdgcn_mfma_f32_16x16x32_bf16(af1, bf0, acc[1][0], 0, 0, 0);
            acc[1][1] = __builtin_amdgcn_mfma_f32_16x16x32_bf16(af1, bf1, acc[1][1], 0, 0, 0);
        }
        __syncthreads();
    }

#pragma unroll
    for (int m = 0; m < 2; ++m) {
#pragma unroll
        for (int r = 0; r < 4; ++r) {
            int gm = m0 + wr * 32 + m * 16 + lkg * 4 + r;
            if (gm >= M) continue;
#pragma unroll
            for (int n = 0; n < 2; ++n) {
                int gn = n0 + wc * 32 + n * 16 + lrow;
                float v = acc[m][n][r];
                if (mode == 0) {
                    ((unsigned short*)C)[(size_t)gm * ldc + gn] = f2bf(v);
                } else if (mode == 1) {
                    float val = (gn >= 192) ? tanhf(v + sv[gn - 192]) : v;
                    ((unsigned short*)C)[(size_t)gm * ldc + gn] = f2bf(val);
                } else {
                    float val = tanhf(v * sv[gn] + tv[gn]);
                    if (flag[0] == 0) val = node_embs[(size_t)gm * EMBD + gn];
                    ((float*)C)[(size_t)gm * EMBD + gn] = val;
                }
            }
        }
    }
}

__global__ __launch_bounds__(256) void gemm_mfma(
    const void* __restrict__ A, int aBf16, int M, int K, int lda,
    const unsigned short* __restrict__ Bn,
    void* __restrict__ C, int ldc, int mode,
    const float* __restrict__ sv, const float* __restrict__ tv,
    const float* __restrict__ node_embs, const int* __restrict__ flag)
{
    __shared__ unsigned short As[64 * 72];
    __shared__ unsigned short Bs[64 * 72];
    gemm_dev(As, Bs, A, aBf16, M, K, lda, Bn, C, ldc, mode, sv, tv, node_embs, flag,
             blockIdx.x * 64, blockIdx.y * 64);
}

// ---------------- K5: XCC-local scatter || C1-GEMM || E1-GEMM ----------------
// Scatter writes into per-XCD-class over-provisioned segments: every line of
// segment p is written ONLY from XCD class p (runtime XCC_ID) -> no cross-L2
// line bouncing, by construction.
__global__ __launch_bounds__(256) void k_mega(
    const float* __restrict__ node_embs, const float* __restrict__ edge_embs,
    const unsigned short* __restrict__ Bn1,
    unsigned short* __restrict__ C1b, unsigned short* __restrict__ E1b,
    const float* __restrict__ br1,
    const int* __restrict__ src, const int* __restrict__ dst,
    const int* __restrict__ evid,
    const int* __restrict__ off_bin, int* __restrict__ cur2,
    unsigned* __restrict__ Rov)
{
    __shared__ unsigned short As[64 * 72];
    __shared__ unsigned short Bs[64 * 72];
    int bid = blockIdx.x;
    if (bid < NBLK_HIST) {
        int e = bid * 256 + threadIdx.x;
        if (e < NE) {
            int part = __builtin_amdgcn_s_getreg(XCC_HWREG) & (NPART - 1);
            int s = src[e], d = dst[e];
            unsigned rv = (unsigned)evid[e] << 15;
            unsigned base = (unsigned)part * SEG;
            int r0 = atomicAdd(&cur2[part * TOT + d], 1);
            Rov[base + off_bin[d] + r0] = (unsigned)s | rv;
            int r1 = atomicAdd(&cur2[part * TOT + NN + s], 1);
            Rov[base + off_bin[NN + s] + r1] = (unsigned)d | rv;
        }
        return;
    }
    int b2 = bid - NBLK_HIST;
    if (b2 < NBLK_GC1) {
        gemm_dev(As, Bs, node_embs, 0, NN, 256, 256, Bn1, C1b, 192, 0,
                 nullptr, nullptr, nullptr, nullptr,
                 (b2 % 313) * 64, (b2 / 313) * 64);
    } else {
        int b3 = b2 - NBLK_GC1;
        gemm_dev(As, Bs, edge_embs, 0, NR, 256, 256, Bn1, E1b, 256, 1,
                 br1, nullptr, nullptr, nullptr,
                 (b3 % 8) * 64, (b3 / 8) * 64);
    }
}

// compact per-part segments -> bin-major R2 (one thread per bin)
__global__ void k_repack(const int* __restrict__ off_bin, const int* __restrict__ cur2,
                         const unsigned* __restrict__ Rov, unsigned* __restrict__ R2)
{
    int bin = blockIdx.x * 256 + threadIdx.x;
    if (bin >= TOT) return;
    int b0 = off_bin[bin];
    int d = b0;
#pragma unroll
    for (int p = 0; p < NPART; ++p) {
        int len = cur2[p * TOT + bin];
        const unsigned* sp = Rov + (size_t)p * SEG + b0;
        for (int i = 0; i < len; ++i) R2[d++] = sp[i];
    }
}

// ---------------- CSR gather, quad-group bf16 rows ----------------

__device__ __forceinline__ void gather_quad(
    const unsigned* __restrict__ R, int r0, int r1, int g, int q,
    const unsigned short* __restrict__ TAB, int ldt, int toff,
    const unsigned short* __restrict__ ETAB, int eoff,
    float4& acc)
{
    int lane = g * 16 + q;
    int cnt = r1 - r0;
    for (int base = 0; base < cnt; base += 64) {
        int rem = cnt - base; if (rem > 64) rem = 64;
        unsigned rec = 0u;
        if (lane < rem) rec = R[r0 + base + lane];
        int i = 0;
        for (; 4 * i + 15 < rem; i += 4) {
            unsigned ra = __shfl(rec, 4 * i + g, 64);
            unsigned rb = __shfl(rec, 4 * i + 4 + g, 64);
            unsigned rc = __shfl(rec, 4 * i + 8 + g, 64);
            unsigned rd = __shfl(rec, 4 * i + 12 + g, 64);
            uint2 ua0 = *(const uint2*)(TAB + (size_t)(ra & 0x7FFFu) * ldt + toff + 4 * q);
            uint2 ue0 = *(const uint2*)(ETAB + (size_t)(ra >> 15) * 256 + eoff + 4 * q);
            uint2 ua1 = *(const uint2*)(TAB + (size_t)(rb & 0x7FFFu) * ldt + toff + 4 * q);
            uint2 ue1 = *(const uint2*)(ETAB + (size_t)(rb >> 15) * 256 + eoff + 4 * q);
            uint2 ua2 = *(const uint2*)(TAB + (size_t)(rc & 0x7FFFu) * ldt + toff + 4 * q);
            uint2 ue2 = *(const uint2*)(ETAB + (size_t)(rc >> 15) * 256 + eoff + 4 * q);
            uint2 ua3 = *(const uint2*)(TAB + (size_t)(rd & 0x7FFFu) * ldt + toff + 4 * q);
            uint2 ue3 = *(const uint2*)(ETAB + (size_t)(rd >> 15) * 256 + eoff + 4 * q);
            float4 a0 = bf4tof4(ua0), e0 = bf4tof4(ue0);
            float4 a1 = bf4tof4(ua1), e1 = bf4tof4(ue1);
            float4 a2 = bf4tof4(ua2), e2 = bf4tof4(ue2);
            float4 a3 = bf4tof4(ua3), e3 = bf4tof4(ue3);
            acc.x += (a0.x - e0.x) + (a1.x - e1.x) + (a2.x - e2.x) + (a3.x - e3.x);
            acc.y += (a0.y - e0.y) + (a1.y - e1.y) + (a2.y - e2.y) + (a3.y - e3.y);
            acc.z += (a0.z - e0.z) + (a1.z - e1.z) + (a2.z - e2.z) + (a3.z - e3.z);
            acc.w += (a0.w - e0.w) + (a1.w - e1.w) + (a2.w - e2.w) + (a3.w - e3.w);
        }
        for (; 4 * i < rem; ++i) {
            int idx = 4 * i + g;
            unsigned rr = __shfl(rec, idx < rem ? idx : 0, 64);
            if (idx < rem) {
                uint2 ua = *(const uint2*)(TAB + (size_t)(rr & 0x7FFFu) * ldt + toff + 4 * q);
                uint2 ue = *(const uint2*)(ETAB + (size_t)(rr >> 15) * 256 + eoff + 4 * q);
                float4 a = bf4tof4(ua), e = bf4tof4(ue);
                acc.x += a.x - e.x; acc.y += a.y - e.y;
                acc.z += a.z - e.z; acc.w += a.w - e.w;
            }
        }
    }
}

__device__ __forceinline__ void xreduce(float4& v)
{
    v.x += __shfl_xor(v.x, 16, 64); v.y += __shfl_xor(v.y, 16, 64);
    v.z += __shfl_xor(v.z, 16, 64); v.w += __shfl_xor(v.w, 16, 64);
    v.x += __shfl_xor(v.x, 32, 64); v.y += __shfl_xor(v.y, 32, 64);
    v.z += __shfl_xor(v.z, 32, 64); v.w += __shfl_xor(v.w, 32, 64);
}

__device__ __forceinline__ uint2 packbf4(float4 o)
{
    return make_uint2((unsigned)f2bf(o.x) | ((unsigned)f2bf(o.y) << 16),
                      (unsigned)f2bf(o.z) | ((unsigned)f2bf(o.w) << 16));
}

// layer 1 fused with combine -> A2b[.,128:192) bf16
__global__ __launch_bounds__(256) void k_gather1(
    const int* __restrict__ off_bin, const unsigned* __restrict__ R2,
    const unsigned short* __restrict__ C1b, const unsigned short* __restrict__ E1b,
    const float* __restrict__ s1, const float* __restrict__ t1,
    unsigned short* __restrict__ A2b)
{
    int n = blockIdx.x * 4 + (threadIdx.x >> 6);
    if (n >= NN) return;
    int lane = threadIdx.x & 63, g = lane >> 4, q = lane & 15;
    int b0 = off_bin[n], b1 = off_bin[n + 1];
    int c0 = off_bin[NN + n], c1 = off_bin[NN + n + 1];
    float di = 1.f / fmaxf((float)(b1 - b0), 1.f);
    float dh = 1.f / fmaxf((float)(c1 - c0), 1.f);
    float4 accO = make_float4(0.f, 0.f, 0.f, 0.f);
    float4 accI = make_float4(0.f, 0.f, 0.f, 0.f);
    gather_quad(R2, b0, b1, g, q, C1b, 192, 0, E1b, 0, accO);
    gather_quad(R2, c0, c1, g, q, C1b, 192, 64, E1b, 64, accI);
    xreduce(accO);
    xreduce(accI);
    if (g == 0) {
        float4 hs = bf4tof4(*(const uint2*)(C1b + (size_t)n * 192 + 128 + 4 * q));
        float4 sv = *(const float4*)(s1 + 4 * q);
        float4 tv = *(const float4*)(t1 + 4 * q);
        float4 o;
        o.x = tanhf((accO.x * di + accI.x * dh + hs.x) * sv.x + tv.x);
        o.y = tanhf((accO.y * di + accI.y * dh + hs.y) * sv.y + tv.y);
        o.z = tanhf((accO.z * di + accI.z * dh + hs.z) * sv.z + tv.z);
        o.w = tanhf((accO.w * di + accI.w * dh + hs.w) * sv.w + tv.w);
        *(uint2*)(A2b + (size_t)n * 192 + 128 + 4 * q) = packbf4(o);
    }
}

// layer 2 -> A2b cols [0,128)
__global__ __launch_bounds__(256) void k_gather2(
    const int* __restrict__ off_bin, const unsigned* __restrict__ R2,
    const unsigned short* __restrict__ A2r, const unsigned short* __restrict__ E1b,
    unsigned short* __restrict__ A2w)
{
    int n = blockIdx.x * 4 + (threadIdx.x >> 6);
    if (n >= NN) return;
    int lane = threadIdx.x & 63, g = lane >> 4, q = lane & 15;
    int b0 = off_bin[n], b1 = off_bin[n + 1];
    int c0 = off_bin[NN + n], c1 = off_bin[NN + n + 1];
    float di = 1.f / fmaxf((float)(b1 - b0), 1.f);
    float dh = 1.f / fmaxf((float)(c1 - c0), 1.f);
    float4 accO = make_float4(0.f, 0.f, 0.f, 0.f);
    float4 accI = make_float4(0.f, 0.f, 0.f, 0.f);
    gather_quad(R2, b0, b1, g, q, A2r, 192, 128, E1b, 192, accO);
    gather_quad(R2, c0, c1, g, q, A2r, 192, 128, E1b, 192, accI);
    xreduce(accO);
    xreduce(accI);
    if (g == 0) {
        float4 o0, o1;
        o0.x = accO.x * di; o0.y = accO.y * di; o0.z = accO.z * di; o0.w = accO.w * di;
        o1.x = accI.x * dh; o1.y = accI.y * dh; o1.z = accI.z * dh; o1.w = accI.w * dh;
        *(uint2*)(A2w + (size_t)n * 192 + 4 * q) = packbf4(o0);
        *(uint2*)(A2w + (size_t)n * 192 + 64 + 4 * q) = packbf4(o1);
    }
}

// ---------------- scoring (tvec fused) ----------------
__global__ __launch_bounds__(256) void k_score(
    const float* __restrict__ hn, const float* __restrict__ rels,
    const int* __restrict__ hids, const int* __restrict__ tids,
    const int* __restrict__ is_head, float* __restrict__ score)
{
    int p = blockIdx.x * 4 + (threadIdx.x >> 6);
    if (p >= BQ * (NN / BQ)) return;
    int l = threadIdx.x & 63;
    int b = p / (NN / BQ);
    int j = p - b * (NN / BQ);
    int idx = (b * NN + 32 * j) / BQ;   // faithful repeat_interleave indexing
    int ih = is_head[0];
    int nid = ih ? tids[b] : hids[b];
    float ssum = 0.f;
#pragma unroll
    for (int q = 0; q < 4; ++q) {
        float r = rels[b * 256 + l + 64 * q];
        float hv = hn[(size_t)nid * 256 + l + 64 * q];
        float tv = ih ? (hv - r) : (hv + r);
        float df = hn[(size_t)idx * 256 + l + 64 * q] - tv;
        ssum = fmaf(df, df, ssum);
    }
#pragma unroll
    for (int off = 32; off >= 1; off >>= 1) ssum += __shfl_xor(ssum, off, 64);
    float dist = sqrtf(ssum);
    float sc = 1.f / (1.f + expf(dist - 12.f));
    if (l < 32) score[(size_t)b * NN + 32 * j + l] = sc;
}

// ---------------- launch ----------------
extern "C" void kernel_launch(void* const* d_in, const int* in_sizes, int n_in,
                              void* d_out, int out_size, void* d_ws, size_t ws_size,
                              hipStream_t stream)
{
    const float* node_embs = (const float*)d_in[0];
    const float* edge_embs = (const float*)d_in[1];
    const float* W_O1 = (const float*)d_in[2];  const float* b_O1 = (const float*)d_in[3];
    const float* W_I1 = (const float*)d_in[4];  const float* b_I1 = (const float*)d_in[5];
    const float* W_S1 = (const float*)d_in[6];  const float* b_S1 = (const float*)d_in[7];
    const float* bn1_g = (const float*)d_in[8]; const float* bn1_b = (const float*)d_in[9];
    const float* bn1_m = (const float*)d_in[10];const float* bn1_v = (const float*)d_in[11];
    const float* Wr1 = (const float*)d_in[12];  const float* br1 = (const float*)d_in[13];
    const float* W_O2 = (const float*)d_in[14]; const float* b_O2 = (const float*)d_in[15];
    const float* W_I2 = (const float*)d_in[16]; const float* b_I2 = (const float*)d_in[17];
    const float* W_S2 = (const float*)d_in[18]; const float* b_S2 = (const float*)d_in[19];
    const float* bn2_g = (const float*)d_in[20];const float* bn2_b = (const float*)d_in[21];
    const float* bn2_m = (const float*)d_in[22];const float* bn2_v = (const float*)d_in[23];
    const float* Wr2 = (const float*)d_in[24];  const float* br2 = (const float*)d_in[25];
    const int* src = (const int*)d_in[26];
    const int* dst = (const int*)d_in[27];
    const int* evid = (const int*)d_in[28];
    const int* hids = (const int*)d_in[29];
    const int* rids = (const int*)d_in[30];
    const int* tids = (const int*)d_in[31];
    const int* upd = (const int*)d_in[32];
    const int* ihead = (const int*)d_in[33];

    unsigned short* C1b = (unsigned short*)d_ws;           // 20000*192
    unsigned short* A2b = C1b + 3840000;                   // 20000*192
    unsigned short* E1b = A2b + 3840000;                   // 500*256
    unsigned short* Bn1 = E1b + 128000;                    // 256*256
    unsigned short* Bn2 = Bn1 + 65536;                     // 256*192

    float* s1   = (float*)(Bn2 + 49152);   // 64
    float* t1   = s1 + 64;                 // 64
    float* s2   = t1 + 64;                 // 256
    float* t2   = s2 + 256;                // 256
    float* rels = t2 + 256;                // 32*256

    unsigned* Rov = (unsigned*)(rels + 8192);  // NPART*SEG over-provisioned records
    unsigned* R2  = Rov + (size_t)NPART * SEG; // 2*NE bin-major records
    int* cur2     = (int*)(R2 + 2 * NE);       // NPART*TOT (memset)
    int* cnt      = cur2 + NPART * TOT;        // TOT (memset, contiguous with cur2)
    int* off_bin  = cnt + TOT;                 // TOT+1
    int* bsum     = off_bin + TOT + 1;         // NB

    float* hn    = (float*)d_out;                       // 20000*256
    float* score = hn + (size_t)NN * EMBD;              // 32*20000

    hipMemsetAsync(cur2, 0, (size_t)(NPART * TOT + TOT) * 4, stream);

    // K1: hist || weight-pack || params || rels-MLP
    k_prep<<<NBLK_K1, 256, 0, stream>>>(
        src, dst, cnt,
        W_O1, W_I1, W_S1, Wr1, W_O2, W_I2, W_S2, Bn1, Bn2,
        b_O1, b_I1, b_S1, bn1_g, bn1_b, bn1_m, bn1_v,
        b_O2, b_I2, b_S2, bn2_g, bn2_b, bn2_m, bn2_v,
        s1, t1, s2, t2,
        edge_embs, br1, br2, Wr2, rids, rels);

    // scan pipeline
    k_scanA<<<NB, 256, 0, stream>>>(cnt, bsum);
    k_scanB<<<1, 64, 0, stream>>>(bsum);
    k_scanC<<<NB, 256, 0, stream>>>(cnt, bsum, off_bin);

    // K5: XCC-local scatter || C1-GEMM || E1-GEMM
    k_mega<<<NBLK_MEGA, 256, 0, stream>>>(node_embs, edge_embs, Bn1,
                                          C1b, E1b, br1, src, dst, evid,
                                          off_bin, cur2, Rov);
    // compact to bin-major
    k_repack<<<(TOT + 255) / 256, 256, 0, stream>>>(off_bin, cur2, Rov, R2);

    // layer-1 aggregation + combine (writes h1 into A2b cols [128,192))
    k_gather1<<<NN / 4, 256, 0, stream>>>(off_bin, R2, C1b, E1b, s1, t1, A2b);
    // layer-2 aggregation (writes A2b cols [0,128))
    k_gather2<<<NN / 4, 256, 0, stream>>>(off_bin, R2, A2b, E1b, A2b);

    // hn = tanh((A2b @ Bn2^T) * s2 + t2)  (or node_embs if !upd)
    gemm_mfma<<<dim3(313, 4), 256, 0, stream>>>(A2b, 1, NN, 192, 192, Bn2,
                                                hn, 256, 2, s2, t2, node_embs, upd);

    // scoring (tvec fused)
    k_score<<<(BQ * (NN / BQ)) / 4, 256, 0, stream>>>(hn, rels, hids, tids, ihead, score);
}

// Round 13
// 144.542 us; speedup vs baseline: 1.2021x; 1.2021x over previous
//
#include <hip/hip_runtime.h>
#include <math.h>

#define NN 20000     // nodes
#define NE 320000    // edges
#define NR 500       // relations
#define EMBD 256
#define D4 64
#define BQ 32        // batch
#define TOT (2 * NN) // concatenated count length
#define NB 40        // scan blocks (40*1024 >= TOT)

#define NBLK_HIST 1250           // (NE+255)/256
#define NBLK_BN 448              // weight-pack blocks
#define NBLK_K1 (NBLK_HIST + NBLK_BN + 2 + BQ)

#define NBLK_GC1 939             // 313*3 C1-GEMM blocks
#define NBLK_GE1 32              // 8*4 E1-GEMM blocks
#define NBLK_MEGA (NBLK_HIST + NBLK_GE1 + NBLK_GC1)

typedef __attribute__((ext_vector_type(8))) short bf16x8;
typedef __attribute__((ext_vector_type(4))) float f32x4;

__device__ __forceinline__ unsigned short f2bf(float x)
{
    unsigned int u = __float_as_uint(x);
    unsigned int r = (u + 0x7fffu + ((u >> 16) & 1u)) >> 16;   // RNE
    return (unsigned short)r;
}

__device__ __forceinline__ float4 bf4tof4(uint2 u)
{
    float4 r;
    r.x = __uint_as_float((u.x & 0xFFFFu) << 16);
    r.y = __uint_as_float(u.x & 0xFFFF0000u);
    r.z = __uint_as_float((u.y & 0xFFFFu) << 16);
    r.w = __uint_as_float(u.y & 0xFFFF0000u);
    return r;
}

// ---------------- K1: hist(+rank capture) | weight pack | params | rels-MLP ----------------
__global__ __launch_bounds__(256) void k_prep(
    const int* __restrict__ src, const int* __restrict__ dst,
    int* __restrict__ cnt, unsigned* __restrict__ rank2,
    const float* __restrict__ W_O1, const float* __restrict__ W_I1,
    const float* __restrict__ W_S1, const float* __restrict__ Wr1,
    const float* __restrict__ W_O2, const float* __restrict__ W_I2,
    const float* __restrict__ W_S2,
    unsigned short* __restrict__ Bn1, unsigned short* __restrict__ Bn2,
    const float* __restrict__ bO1, const float* __restrict__ bI1,
    const float* __restrict__ bS1,
    const float* __restrict__ g1, const float* __restrict__ bb1,
    const float* __restrict__ m1, const float* __restrict__ v1,
    const float* __restrict__ bO2, const float* __restrict__ bI2,
    const float* __restrict__ bS2,
    const float* __restrict__ g2, const float* __restrict__ bb2,
    const float* __restrict__ m2, const float* __restrict__ v2,
    float* __restrict__ s1, float* __restrict__ t1,
    float* __restrict__ s2, float* __restrict__ t2,
    const float* __restrict__ edge_embs,
    const float* __restrict__ br1, const float* __restrict__ br2,
    const float* __restrict__ Wr2full, const int* __restrict__ rids,
    float* __restrict__ rels)
{
    int b = blockIdx.x;
    if (b < NBLK_HIST) {
        int i = b * 256 + threadIdx.x;
        if (i < NE) {
            int r_in = atomicAdd(&cnt[dst[i]], 1);
            int r_out = atomicAdd(&cnt[NN + src[i]], 1);
            rank2[i] = (unsigned)r_in | ((unsigned)r_out << 16);
        }
        return;
    }
    b -= NBLK_HIST;
    if (b < NBLK_BN) {
        int id = b * 256 + threadIdx.x;
        if (id < 256 * 256) {
            int n = id >> 8, k = id & 255;
            float v;
            if (n < 64)       v = W_O1[n * 256 + k];
            else if (n < 128) v = W_I1[(n - 64) * 256 + k];
            else if (n < 192) v = W_S1[(n - 128) * 256 + k];
            else              v = Wr1[(n - 192) * 256 + k];
            Bn1[id] = f2bf(v);
        } else {
            int id2 = id - 256 * 256;
            if (id2 < 256 * 192) {
                int n = id2 / 192, k = id2 - n * 192;
                float v;
                if (k < 64)       v = W_O2[n * 64 + k];
                else if (k < 128) v = W_I2[n * 64 + (k - 64)];
                else              v = W_S2[n * 64 + (k - 128)];
                Bn2[id2] = f2bf(v);
            }
        }
        return;
    }
    b -= NBLK_BN;
    if (b < 2) {
        int i = b * 256 + threadIdx.x;   // [0,512)
        if (i < 64) {
            float rsg = g1[i] / sqrtf(v1[i] + 1e-5f);
            s1[i] = rsg * (1.f / 3.f);
            t1[i] = ((bO1[i] + bI1[i] + bS1[i]) * (1.f / 3.f) - m1[i]) * rsg + bb1[i];
        } else if (i < 320) {
            int n = i - 64;
            float rsg = g2[n] / sqrtf(v2[n] + 1e-5f);
            s2[n] = rsg * (1.f / 3.f);
            t2[n] = ((bO2[n] + bI2[n] + bS2[n]) * (1.f / 3.f) - m2[n]) * rsg + bb2[n];
        }
        return;
    }
    // rels MLP: rels[rb] = relu(edge_embs[rids[rb]] @ Wr1^T + br1) @ Wr2^T + br2
    {
        __shared__ float e_s[256];
        __shared__ float m_s[64];
        int rb = b - 2, o = threadIdx.x;
        int rid = rids[rb];
        e_s[o] = edge_embs[(size_t)rid * 256 + o];
        __syncthreads();
        if (o < 64) {
            float acc = br1[o];
            for (int k = 0; k < 256; ++k) acc = fmaf(e_s[k], Wr1[o * 256 + k], acc);
            m_s[o] = fmaxf(acc, 0.f);
        }
        __syncthreads();
        float r = br2[o];
        for (int jj = 0; jj < 64; ++jj) r = fmaf(m_s[jj], Wr2full[o * 64 + jj], r);
        rels[rb * 256 + o] = r;
    }
}

// ---------------- fused scan (single kernel, spin barrier; 40 co-resident blocks) ----------------
__global__ __launch_bounds__(256) void k_scan(const int* __restrict__ cnt,
                                              int* __restrict__ off_bin,
                                              int* __restrict__ bsum,
                                              int* __restrict__ flag)
{
    __shared__ int lds[256];
    __shared__ int pre_s;
    int t = threadIdx.x, bid = blockIdx.x;
    int base = bid * 1024 + t * 4;
    int e0 = 0, e1 = 0, e2 = 0, e3 = 0;
    if (base + 3 < TOT) {
        int4 v = *(const int4*)(cnt + base);
        e0 = v.x; e1 = v.y; e2 = v.z; e3 = v.w;
    } else {
        if (base + 0 < TOT) e0 = cnt[base + 0];
        if (base + 1 < TOT) e1 = cnt[base + 1];
        if (base + 2 < TOT) e2 = cnt[base + 2];
        if (base + 3 < TOT) e3 = cnt[base + 3];
    }
    int s = e0 + e1 + e2 + e3;
    lds[t] = s;
    __syncthreads();
    for (int d = 1; d < 256; d <<= 1) {
        int u = (t >= d) ? lds[t - d] : 0;
        __syncthreads();
        lds[t] += u;
        __syncthreads();
    }
    // publish block total, device-scope barrier (all 40 blocks co-resident)
    if (t == 255) {
        bsum[bid] = lds[255];
        __threadfence();
        atomicAdd(flag, 1);
    }
    if (t == 0) {
        while (atomicAdd(flag, 0) < NB) { }
    }
    __syncthreads();
    __threadfence();
    if (t < 64) {
        int v = (t < bid) ? atomicAdd(&bsum[t], 0) : 0;
#pragma unroll
        for (int d = 32; d >= 1; d >>= 1) v += __shfl_xor(v, d, 64);
        if (t == 0) pre_s = v;
    }
    __syncthreads();
    int run = lds[t] - s + pre_s;
    if (base + 3 < TOT) {
        int4 o = make_int4(run, run + e0, run + e0 + e1, run + e0 + e1 + e2);
        *(int4*)(off_bin + base) = o;
    } else {
        int r = run;
        if (base + 0 < TOT) { off_bin[base + 0] = r; r += e0; }
        if (base + 1 < TOT) { off_bin[base + 1] = r; r += e1; }
        if (base + 2 < TOT) { off_bin[base + 2] = r; r += e2; }
        if (base + 3 < TOT) { off_bin[base + 3] = r; r += e3; }
    }
    if (bid == 0 && t == 0) off_bin[TOT] = 2 * NE;
}

// ---------------- MFMA bf16 GEMM body ----------------
__device__ __forceinline__ void gemm_dev(
    unsigned short* As, unsigned short* Bs,
    const void* __restrict__ Av, int aBf16, int M, int K, int lda,
    const unsigned short* __restrict__ Bn,
    void* __restrict__ C, int ldc, int mode,
    const float* __restrict__ sv, const float* __restrict__ tv,
    const float* __restrict__ node_embs, const int* __restrict__ flag,
    int m0, int n0)
{
    const int t = threadIdx.x;
    const int lane = t & 63, wave = t >> 6;
    const int wr = wave >> 1, wc = wave & 1;
    const int lrow = lane & 15, lkg = lane >> 4;

    f32x4 acc[2][2] = {};

    for (int kb = 0; kb < K; kb += 64) {
        if (aBf16) {
            const unsigned short* A = (const unsigned short*)Av;
#pragma unroll
            for (int it = 0; it < 2; ++it) {
                int idx = t + it * 256;
                int ko = idx & 7;
                int row = idx >> 3;
                int gm = m0 + row;
                uint4 a = make_uint4(0u, 0u, 0u, 0u);
                if (gm < M) a = *(const uint4*)(A + (size_t)gm * lda + kb + 8 * ko);
                *(uint4*)&As[row * 72 + 8 * ko] = a;
            }
        } else {
            const float* A = (const float*)Av;
#pragma unroll
            for (int it = 0; it < 4; ++it) {
                int idx = t + it * 256;
                int kq = idx & 15;
                int row = idx >> 4;
                int gm = m0 + row;
                float4 a = make_float4(0.f, 0.f, 0.f, 0.f);
                if (gm < M) a = *(const float4*)(A + (size_t)gm * lda + kb + 4 * kq);
                unsigned int p0 = (unsigned int)f2bf(a.x) | ((unsigned int)f2bf(a.y) << 16);
                unsigned int p1 = (unsigned int)f2bf(a.z) | ((unsigned int)f2bf(a.w) << 16);
                *(uint2*)&As[row * 72 + 4 * kq] = make_uint2(p0, p1);
            }
        }
#pragma unroll
        for (int it = 0; it < 2; ++it) {
            int idx = t + it * 256;
            int ko = idx & 7;
            int row = idx >> 3;
            uint4 b = *(const uint4*)(Bn + (size_t)(n0 + row) * K + kb + 8 * ko);
            *(uint4*)&Bs[row * 72 + 8 * ko] = b;
        }
        __syncthreads();
#pragma unroll
        for (int ks = 0; ks < 2; ++ks) {
            int k0 = ks * 32 + lkg * 8;
            bf16x8 af0 = *(const bf16x8*)&As[(wr * 32 + lrow) * 72 + k0];
            bf16x8 af1 = *(const bf16x8*)&As[(wr * 32 + 16 + lrow) * 72 + k0];
            bf16x8 bf0 = *(const bf16x8*)&Bs[(wc * 32 + lrow) * 72 + k0];
            bf16x8 bf1 = *(const bf16x8*)&Bs[(wc * 32 + 16 + lrow) * 72 + k0];
            acc[0][0] = __builtin_amdgcn_mfma_f32_16x16x32_bf16(af0, bf0, acc[0][0], 0, 0, 0);
            acc[0][1] = __builtin_amdgcn_mfma_f32_16x16x32_bf16(af0, bf1, acc[0][1], 0, 0, 0);
            acc[1][0] = __builtin_amdgcn_mfma_f32_16x16x32_bf16(af1, bf0, acc[1][0], 0, 0, 0);
            acc[1][1] = __builtin_amdgcn_mfma_f32_16x16x32_bf16(af1, bf1, acc[1][1], 0, 0, 0);
        }
        __syncthreads();
    }

#pragma unroll
    for (int m = 0; m < 2; ++m) {
#pragma unroll
        for (int r = 0; r < 4; ++r) {
            int gm = m0 + wr * 32 + m * 16 + lkg * 4 + r;
            if (gm >= M) continue;
#pragma unroll
            for (int n = 0; n < 2; ++n) {
                int gn = n0 + wc * 32 + n * 16 + lrow;
                float v = acc[m][n][r];
                if (mode == 0) {
                    ((unsigned short*)C)[(size_t)gm * ldc + gn] = f2bf(v);
                } else if (mode == 1) {
                    float val = (gn >= 192) ? tanhf(v + sv[gn - 192]) : v;
                    ((unsigned short*)C)[(size_t)gm * ldc + gn] = f2bf(val);
                } else {
                    float val = tanhf(v * sv[gn] + tv[gn]);
                    if (flag[0] == 0) val = node_embs[(size_t)gm * EMBD + gn];
                    ((float*)C)[(size_t)gm * EMBD + gn] = val;
                }
            }
        }
    }
}

__global__ __launch_bounds__(256) void gemm_mfma(
    const void* __restrict__ A, int aBf16, int M, int K, int lda,
    const unsigned short* __restrict__ Bn,
    void* __restrict__ C, int ldc, int mode,
    const float* __restrict__ sv, const float* __restrict__ tv,
    const float* __restrict__ node_embs, const int* __restrict__ flag)
{
    __shared__ unsigned short As[64 * 72];
    __shared__ unsigned short Bs[64 * 72];
    gemm_dev(As, Bs, A, aBf16, M, K, lda, Bn, C, ldc, mode, sv, tv, node_embs, flag,
             blockIdx.x * 64, blockIdx.y * 64);
}

// ---------------- K5: scatter (atomic-free, FIRST) || E1-GEMM || C1-GEMM ----------------
__global__ __launch_bounds__(256) void k_mega(
    const float* __restrict__ node_embs, const float* __restrict__ edge_embs,
    const unsigned short* __restrict__ Bn1,
    unsigned short* __restrict__ C1b, unsigned short* __restrict__ E1b,
    const float* __restrict__ br1,
    const int* __restrict__ src, const int* __restrict__ dst,
    const int* __restrict__ evid, const unsigned* __restrict__ rank2,
    const int* __restrict__ offc, unsigned* __restrict__ R)
{
    __shared__ unsigned short As[64 * 72];
    __shared__ unsigned short Bs[64 * 72];
    int bid = blockIdx.x;
    if (bid < NBLK_HIST) {
        // scatter first: the latency-bound long pole starts at t=0
        int e = bid * 256 + threadIdx.x;
        if (e < NE) {
            int s = src[e], d = dst[e];
            unsigned rv = (unsigned)evid[e] << 15;
            unsigned rk = rank2[e];
            R[offc[d] + (rk & 0xFFFFu)] = (unsigned)s | rv;
            R[offc[NN + s] + (rk >> 16)] = (unsigned)d | rv;
        }
        return;
    }
    int b2 = bid - NBLK_HIST;
    if (b2 < NBLK_GE1) {
        // E1b = bf16( edge_embs @ Bn1^T ), fused er1 tanh on cols [192,256)
        gemm_dev(As, Bs, edge_embs, 0, NR, 256, 256, Bn1, E1b, 256, 1,
                 br1, nullptr, nullptr, nullptr,
                 (b2 % 8) * 64, (b2 / 8) * 64);
    } else {
        int b3 = b2 - NBLK_GE1;
        // C1b = bf16( node_embs @ Bn1[0:192]^T )
        gemm_dev(As, Bs, node_embs, 0, NN, 256, 256, Bn1, C1b, 192, 0,
                 nullptr, nullptr, nullptr, nullptr,
                 (b3 % 313) * 64, (b3 / 313) * 64);
    }
}

// ---------------- CSR gather, quad-group bf16 rows ----------------

__device__ __forceinline__ void gather_quad(
    const unsigned* __restrict__ R, int r0, int r1, int g, int q,
    const unsigned short* __restrict__ TAB, int ldt, int toff,
    const unsigned short* __restrict__ ETAB, int eoff,
    float4& acc)
{
    int lane = g * 16 + q;
    int cnt = r1 - r0;
    for (int base = 0; base < cnt; base += 64) {
        int rem = cnt - base; if (rem > 64) rem = 64;
        unsigned rec = 0u;
        if (lane < rem) rec = R[r0 + base + lane];
        int i = 0;
        for (; 4 * i + 15 < rem; i += 4) {
            unsigned ra = __shfl(rec, 4 * i + g, 64);
            unsigned rb = __shfl(rec, 4 * i + 4 + g, 64);
            unsigned rc = __shfl(rec, 4 * i + 8 + g, 64);
            unsigned rd = __shfl(rec, 4 * i + 12 + g, 64);
            uint2 ua0 = *(const uint2*)(TAB + (size_t)(ra & 0x7FFFu) * ldt + toff + 4 * q);
            uint2 ue0 = *(const uint2*)(ETAB + (size_t)(ra >> 15) * 256 + eoff + 4 * q);
            uint2 ua1 = *(const uint2*)(TAB + (size_t)(rb & 0x7FFFu) * ldt + toff + 4 * q);
            uint2 ue1 = *(const uint2*)(ETAB + (size_t)(rb >> 15) * 256 + eoff + 4 * q);
            uint2 ua2 = *(const uint2*)(TAB + (size_t)(rc & 0x7FFFu) * ldt + toff + 4 * q);
            uint2 ue2 = *(const uint2*)(ETAB + (size_t)(rc >> 15) * 256 + eoff + 4 * q);
            uint2 ua3 = *(const uint2*)(TAB + (size_t)(rd & 0x7FFFu) * ldt + toff + 4 * q);
            uint2 ue3 = *(const uint2*)(ETAB + (size_t)(rd >> 15) * 256 + eoff + 4 * q);
            float4 a0 = bf4tof4(ua0), e0 = bf4tof4(ue0);
            float4 a1 = bf4tof4(ua1), e1 = bf4tof4(ue1);
            float4 a2 = bf4tof4(ua2), e2 = bf4tof4(ue2);
            float4 a3 = bf4tof4(ua3), e3 = bf4tof4(ue3);
            acc.x += (a0.x - e0.x) + (a1.x - e1.x) + (a2.x - e2.x) + (a3.x - e3.x);
            acc.y += (a0.y - e0.y) + (a1.y - e1.y) + (a2.y - e2.y) + (a3.y - e3.y);
            acc.z += (a0.z - e0.z) + (a1.z - e1.z) + (a2.z - e2.z) + (a3.z - e3.z);
            acc.w += (a0.w - e0.w) + (a1.w - e1.w) + (a2.w - e2.w) + (a3.w - e3.w);
        }
        for (; 4 * i < rem; ++i) {
            int idx = 4 * i + g;
            unsigned rr = __shfl(rec, idx < rem ? idx : 0, 64);
            if (idx < rem) {
                uint2 ua = *(const uint2*)(TAB + (size_t)(rr & 0x7FFFu) * ldt + toff + 4 * q);
                uint2 ue = *(const uint2*)(ETAB + (size_t)(rr >> 15) * 256 + eoff + 4 * q);
                float4 a = bf4tof4(ua), e = bf4tof4(ue);
                acc.x += a.x - e.x; acc.y += a.y - e.y;
                acc.z += a.z - e.z; acc.w += a.w - e.w;
            }
        }
    }
}

__device__ __forceinline__ void xreduce(float4& v)
{
    v.x += __shfl_xor(v.x, 16, 64); v.y += __shfl_xor(v.y, 16, 64);
    v.z += __shfl_xor(v.z, 16, 64); v.w += __shfl_xor(v.w, 16, 64);
    v.x += __shfl_xor(v.x, 32, 64); v.y += __shfl_xor(v.y, 32, 64);
    v.z += __shfl_xor(v.z, 32, 64); v.w += __shfl_xor(v.w, 32, 64);
}

__device__ __forceinline__ uint2 packbf4(float4 o)
{
    return make_uint2((unsigned)f2bf(o.x) | ((unsigned)f2bf(o.y) << 16),
                      (unsigned)f2bf(o.z) | ((unsigned)f2bf(o.w) << 16));
}

// layer 1 fused with combine -> A2b[.,128:192) bf16
__global__ __launch_bounds__(256) void k_gather1(
    const int* __restrict__ offc, const unsigned* __restrict__ R,
    const unsigned short* __restrict__ C1b, const unsigned short* __restrict__ E1b,
    const float* __restrict__ s1, const float* __restrict__ t1,
    unsigned short* __restrict__ A2b)
{
    int n = blockIdx.x * 4 + (threadIdx.x >> 6);
    if (n >= NN) return;
    int lane = threadIdx.x & 63, g = lane >> 4, q = lane & 15;
    int b0 = offc[n], b1 = offc[n + 1];
    int c0 = offc[NN + n], c1 = offc[NN + n + 1];
    float di = 1.f / fmaxf((float)(b1 - b0), 1.f);
    float dh = 1.f / fmaxf((float)(c1 - c0), 1.f);
    float4 accO = make_float4(0.f, 0.f, 0.f, 0.f);
    float4 accI = make_float4(0.f, 0.f, 0.f, 0.f);
    gather_quad(R, b0, b1, g, q, C1b, 192, 0, E1b, 0, accO);
    gather_quad(R, c0, c1, g, q, C1b, 192, 64, E1b, 64, accI);
    xreduce(accO);
    xreduce(accI);
    if (g == 0) {
        float4 hs = bf4tof4(*(const uint2*)(C1b + (size_t)n * 192 + 128 + 4 * q));
        float4 sv = *(const float4*)(s1 + 4 * q);
        float4 tv = *(const float4*)(t1 + 4 * q);
        float4 o;
        o.x = tanhf((accO.x * di + accI.x * dh + hs.x) * sv.x + tv.x);
        o.y = tanhf((accO.y * di + accI.y * dh + hs.y) * sv.y + tv.y);
        o.z = tanhf((accO.z * di + accI.z * dh + hs.z) * sv.z + tv.z);
        o.w = tanhf((accO.w * di + accI.w * dh + hs.w) * sv.w + tv.w);
        *(uint2*)(A2b + (size_t)n * 192 + 128 + 4 * q) = packbf4(o);
    }
}

// layer 2 -> A2b cols [0,128)
__global__ __launch_bounds__(256) void k_gather2(
    const int* __restrict__ offc, const unsigned* __restrict__ R,
    const unsigned short* __restrict__ A2r, const unsigned short* __restrict__ E1b,
    unsigned short* __restrict__ A2w)
{
    int n = blockIdx.x * 4 + (threadIdx.x >> 6);
    if (n >= NN) return;
    int lane = threadIdx.x & 63, g = lane >> 4, q = lane & 15;
    int b0 = offc[n], b1 = offc[n + 1];
    int c0 = offc[NN + n], c1 = offc[NN + n + 1];
    float di = 1.f / fmaxf((float)(b1 - b0), 1.f);
    float dh = 1.f / fmaxf((float)(c1 - c0), 1.f);
    float4 accO = make_float4(0.f, 0.f, 0.f, 0.f);
    float4 accI = make_float4(0.f, 0.f, 0.f, 0.f);
    gather_quad(R, b0, b1, g, q, A2r, 192, 128, E1b, 192, accO);
    gather_quad(R, c0, c1, g, q, A2r, 192, 128, E1b, 192, accI);
    xreduce(accO);
    xreduce(accI);
    if (g == 0) {
        float4 o0, o1;
        o0.x = accO.x * di; o0.y = accO.y * di; o0.z = accO.z * di; o0.w = accO.w * di;
        o1.x = accI.x * dh; o1.y = accI.y * dh; o1.z = accI.z * dh; o1.w = accI.w * dh;
        *(uint2*)(A2w + (size_t)n * 192 + 4 * q) = packbf4(o0);
        *(uint2*)(A2w + (size_t)n * 192 + 64 + 4 * q) = packbf4(o1);
    }
}

// ---------------- scoring (tvec fused) ----------------
__global__ __launch_bounds__(256) void k_score(
    const float* __restrict__ hn, const float* __restrict__ rels,
    const int* __restrict__ hids, const int* __restrict__ tids,
    const int* __restrict__ is_head, float* __restrict__ score)
{
    int p = blockIdx.x * 4 + (threadIdx.x >> 6);
    if (p >= BQ * (NN / BQ)) return;
    int l = threadIdx.x & 63;
    int b = p / (NN / BQ);
    int j = p - b * (NN / BQ);
    int idx = (b * NN + 32 * j) / BQ;   // faithful repeat_interleave indexing
    int ih = is_head[0];
    int nid = ih ? tids[b] : hids[b];
    float ssum = 0.f;
#pragma unroll
    for (int q = 0; q < 4; ++q) {
        float r = rels[b * 256 + l + 64 * q];
        float hv = hn[(size_t)nid * 256 + l + 64 * q];
        float tv = ih ? (hv - r) : (hv + r);
        float df = hn[(size_t)idx * 256 + l + 64 * q] - tv;
        ssum = fmaf(df, df, ssum);
    }
#pragma unroll
    for (int off = 32; off >= 1; off >>= 1) ssum += __shfl_xor(ssum, off, 64);
    float dist = sqrtf(ssum);
    float sc = 1.f / (1.f + expf(dist - 12.f));
    if (l < 32) score[(size_t)b * NN + 32 * j + l] = sc;
}

// ---------------- launch ----------------
extern "C" void kernel_launch(void* const* d_in, const int* in_sizes, int n_in,
                              void* d_out, int out_size, void* d_ws, size_t ws_size,
                              hipStream_t stream)
{
    const float* node_embs = (const float*)d_in[0];
    const float* edge_embs = (const float*)d_in[1];
    const float* W_O1 = (const float*)d_in[2];  const float* b_O1 = (const float*)d_in[3];
    const float* W_I1 = (const float*)d_in[4];  const float* b_I1 = (const float*)d_in[5];
    const float* W_S1 = (const float*)d_in[6];  const float* b_S1 = (const float*)d_in[7];
    const float* bn1_g = (const float*)d_in[8]; const float* bn1_b = (const float*)d_in[9];
    const float* bn1_m = (const float*)d_in[10];const float* bn1_v = (const float*)d_in[11];
    const float* Wr1 = (const float*)d_in[12];  const float* br1 = (const float*)d_in[13];
    const float* W_O2 = (const float*)d_in[14]; const float* b_O2 = (const float*)d_in[15];
    const float* W_I2 = (const float*)d_in[16]; const float* b_I2 = (const float*)d_in[17];
    const float* W_S2 = (const float*)d_in[18]; const float* b_S2 = (const float*)d_in[19];
    const float* bn2_g = (const float*)d_in[20];const float* bn2_b = (const float*)d_in[21];
    const float* bn2_m = (const float*)d_in[22];const float* bn2_v = (const float*)d_in[23];
    const float* Wr2 = (const float*)d_in[24];  const float* br2 = (const float*)d_in[25];
    const int* src = (const int*)d_in[26];
    const int* dst = (const int*)d_in[27];
    const int* evid = (const int*)d_in[28];
    const int* hids = (const int*)d_in[29];
    const int* rids = (const int*)d_in[30];
    const int* tids = (const int*)d_in[31];
    const int* upd = (const int*)d_in[32];
    const int* ihead = (const int*)d_in[33];

    unsigned short* C1b = (unsigned short*)d_ws;           // 20000*192
    unsigned short* A2b = C1b + 3840000;                   // 20000*192
    unsigned short* E1b = A2b + 3840000;                   // 500*256
    unsigned short* Bn1 = E1b + 128000;                    // 256*256
    unsigned short* Bn2 = Bn1 + 65536;                     // 256*192

    float* s1   = (float*)(Bn2 + 49152);   // 64
    float* t1   = s1 + 64;                 // 64
    float* s2   = t1 + 64;                 // 256
    float* t2   = s2 + 256;                // 256
    float* rels = t2 + 256;                // 32*256

    unsigned* R     = (unsigned*)(rels + 8192);  // 2*NE packed records
    unsigned* rank2 = R + 2 * NE;                // NE (rank_in | rank_out<<16)
    int* cnt    = (int*)(rank2 + NE);      // TOT   (memset)
    int* flag   = cnt + TOT;               // 1     (memset, contiguous)
    int* off_bin= flag + 1;                // TOT+1
    int* bsum   = off_bin + TOT + 1;       // NB

    float* hn    = (float*)d_out;                       // 20000*256
    float* score = hn + (size_t)NN * EMBD;              // 32*20000

    hipMemsetAsync(cnt, 0, (size_t)(TOT + 1) * 4, stream);

    // K1: hist(+ranks) || weight-pack || params || rels-MLP
    k_prep<<<NBLK_K1, 256, 0, stream>>>(
        src, dst, cnt, rank2,
        W_O1, W_I1, W_S1, Wr1, W_O2, W_I2, W_S2, Bn1, Bn2,
        b_O1, b_I1, b_S1, bn1_g, bn1_b, bn1_m, bn1_v,
        b_O2, b_I2, b_S2, bn2_g, bn2_b, bn2_m, bn2_v,
        s1, t1, s2, t2,
        edge_embs, br1, br2, Wr2, rids, rels);

    // fused scan (1 kernel)
    k_scan<<<NB, 256, 0, stream>>>(cnt, off_bin, bsum, flag);

    // K5: scatter-first || E1-GEMM || C1-GEMM
    k_mega<<<NBLK_MEGA, 256, 0, stream>>>(node_embs, edge_embs, Bn1,
                                          C1b, E1b, br1, src, dst, evid, rank2, off_bin, R);

    // layer-1 aggregation + combine (writes h1 into A2b cols [128,192))
    k_gather1<<<NN / 4, 256, 0, stream>>>(off_bin, R, C1b, E1b, s1, t1, A2b);
    // layer-2 aggregation (writes A2b cols [0,128))
    k_gather2<<<NN / 4, 256, 0, stream>>>(off_bin, R, A2b, E1b, A2b);

    // hn = tanh((A2b @ Bn2^T) * s2 + t2)  (or node_embs if !upd)
    gemm_mfma<<<dim3(313, 4), 256, 0, stream>>>(A2b, 1, NN, 192, 192, Bn2,
                                                hn, 256, 2, s2, t2, node_embs, upd);

    // scoring (tvec fused)
    k_score<<<(BQ * (NN / BQ)) / 4, 256, 0, stream>>>(hn, rels, hids, tids, ihead, score);
}

// Round 14
// 144.360 us; speedup vs baseline: 1.2036x; 1.0013x over previous
//
#include <hip/hip_runtime.h>
#include <math.h>

#define NN 20000     // nodes
#define NE 320000    // edges
#define NR 500       // relations
#define EMBD 256
#define D4 64
#define BQ 32        // batch
#define TOT (2 * NN) // interleaved bins: 2n = IN(n), 2n+1 = OUT(n)
#define NB 40        // scan blocks (40*1024 >= TOT)

#define NBLK_HIST 1250           // (NE+255)/256
#define NBLK_BN 448              // weight-pack blocks
#define NBLK_K1 (NBLK_HIST + NBLK_BN + 2 + BQ)

#define NBLK_GC1 939             // 313*3 C1-GEMM blocks
#define NBLK_GE1 32              // 8*4 E1-GEMM blocks
#define NBLK_MEGA (NBLK_HIST + NBLK_GE1 + NBLK_GC1)

typedef __attribute__((ext_vector_type(8))) short bf16x8;
typedef __attribute__((ext_vector_type(4))) float f32x4;

__device__ __forceinline__ unsigned short f2bf(float x)
{
    unsigned int u = __float_as_uint(x);
    unsigned int r = (u + 0x7fffu + ((u >> 16) & 1u)) >> 16;   // RNE
    return (unsigned short)r;
}

__device__ __forceinline__ float4 bf4tof4(uint2 u)
{
    float4 r;
    r.x = __uint_as_float((u.x & 0xFFFFu) << 16);
    r.y = __uint_as_float(u.x & 0xFFFF0000u);
    r.z = __uint_as_float((u.y & 0xFFFFu) << 16);
    r.w = __uint_as_float(u.y & 0xFFFF0000u);
    return r;
}

// ---------------- K1: hist(+rank capture, interleaved bins) | weight pack | params | rels-MLP ----------------
__global__ __launch_bounds__(256) void k_prep(
    const int* __restrict__ src, const int* __restrict__ dst,
    int* __restrict__ cnt, unsigned* __restrict__ rank2,
    const float* __restrict__ W_O1, const float* __restrict__ W_I1,
    const float* __restrict__ W_S1, const float* __restrict__ Wr1,
    const float* __restrict__ W_O2, const float* __restrict__ W_I2,
    const float* __restrict__ W_S2,
    unsigned short* __restrict__ Bn1, unsigned short* __restrict__ Bn2,
    const float* __restrict__ bO1, const float* __restrict__ bI1,
    const float* __restrict__ bS1,
    const float* __restrict__ g1, const float* __restrict__ bb1,
    const float* __restrict__ m1, const float* __restrict__ v1,
    const float* __restrict__ bO2, const float* __restrict__ bI2,
    const float* __restrict__ bS2,
    const float* __restrict__ g2, const float* __restrict__ bb2,
    const float* __restrict__ m2, const float* __restrict__ v2,
    float* __restrict__ s1, float* __restrict__ t1,
    float* __restrict__ s2, float* __restrict__ t2,
    const float* __restrict__ edge_embs,
    const float* __restrict__ br1, const float* __restrict__ br2,
    const float* __restrict__ Wr2full, const int* __restrict__ rids,
    float* __restrict__ rels)
{
    int b = blockIdx.x;
    if (b < NBLK_HIST) {
        int i = b * 256 + threadIdx.x;
        if (i < NE) {
            int r_in = atomicAdd(&cnt[2 * dst[i]], 1);
            int r_out = atomicAdd(&cnt[2 * src[i] + 1], 1);
            rank2[i] = (unsigned)r_in | ((unsigned)r_out << 16);
        }
        return;
    }
    b -= NBLK_HIST;
    if (b < NBLK_BN) {
        int id = b * 256 + threadIdx.x;
        if (id < 256 * 256) {
            int n = id >> 8, k = id & 255;
            float v;
            if (n < 64)       v = W_O1[n * 256 + k];
            else if (n < 128) v = W_I1[(n - 64) * 256 + k];
            else if (n < 192) v = W_S1[(n - 128) * 256 + k];
            else              v = Wr1[(n - 192) * 256 + k];
            Bn1[id] = f2bf(v);
        } else {
            int id2 = id - 256 * 256;
            if (id2 < 256 * 192) {
                int n = id2 / 192, k = id2 - n * 192;
                float v;
                if (k < 64)       v = W_O2[n * 64 + k];
                else if (k < 128) v = W_I2[n * 64 + (k - 64)];
                else              v = W_S2[n * 64 + (k - 128)];
                Bn2[id2] = f2bf(v);
            }
        }
        return;
    }
    b -= NBLK_BN;
    if (b < 2) {
        int i = b * 256 + threadIdx.x;   // [0,512)
        if (i < 64) {
            float rsg = g1[i] / sqrtf(v1[i] + 1e-5f);
            s1[i] = rsg * (1.f / 3.f);
            t1[i] = ((bO1[i] + bI1[i] + bS1[i]) * (1.f / 3.f) - m1[i]) * rsg + bb1[i];
        } else if (i < 320) {
            int n = i - 64;
            float rsg = g2[n] / sqrtf(v2[n] + 1e-5f);
            s2[n] = rsg * (1.f / 3.f);
            t2[n] = ((bO2[n] + bI2[n] + bS2[n]) * (1.f / 3.f) - m2[n]) * rsg + bb2[n];
        }
        return;
    }
    // rels MLP
    {
        __shared__ float e_s[256];
        __shared__ float m_s[64];
        int rb = b - 2, o = threadIdx.x;
        int rid = rids[rb];
        e_s[o] = edge_embs[(size_t)rid * 256 + o];
        __syncthreads();
        if (o < 64) {
            float acc = br1[o];
            for (int k = 0; k < 256; ++k) acc = fmaf(e_s[k], Wr1[o * 256 + k], acc);
            m_s[o] = fmaxf(acc, 0.f);
        }
        __syncthreads();
        float r = br2[o];
        for (int jj = 0; jj < 64; ++jj) r = fmaf(m_s[jj], Wr2full[o * 64 + jj], r);
        rels[rb * 256 + o] = r;
    }
}

// ---------------- fused scan (single kernel, spin barrier; 40 co-resident blocks) ----------------
__global__ __launch_bounds__(256) void k_scan(const int* __restrict__ cnt,
                                              int* __restrict__ off_bin,
                                              int* __restrict__ bsum,
                                              int* __restrict__ flag)
{
    __shared__ int lds[256];
    __shared__ int pre_s;
    int t = threadIdx.x, bid = blockIdx.x;
    int base = bid * 1024 + t * 4;
    int e0 = 0, e1 = 0, e2 = 0, e3 = 0;
    if (base + 3 < TOT) {
        int4 v = *(const int4*)(cnt + base);
        e0 = v.x; e1 = v.y; e2 = v.z; e3 = v.w;
    } else {
        if (base + 0 < TOT) e0 = cnt[base + 0];
        if (base + 1 < TOT) e1 = cnt[base + 1];
        if (base + 2 < TOT) e2 = cnt[base + 2];
        if (base + 3 < TOT) e3 = cnt[base + 3];
    }
    int s = e0 + e1 + e2 + e3;
    lds[t] = s;
    __syncthreads();
    for (int d = 1; d < 256; d <<= 1) {
        int u = (t >= d) ? lds[t - d] : 0;
        __syncthreads();
        lds[t] += u;
        __syncthreads();
    }
    if (t == 255) {
        bsum[bid] = lds[255];
        __threadfence();
        atomicAdd(flag, 1);
    }
    if (t == 0) {
        while (atomicAdd(flag, 0) < NB) { }
    }
    __syncthreads();
    __threadfence();
    if (t < 64) {
        int v = (t < bid) ? atomicAdd(&bsum[t], 0) : 0;
#pragma unroll
        for (int d = 32; d >= 1; d >>= 1) v += __shfl_xor(v, d, 64);
        if (t == 0) pre_s = v;
    }
    __syncthreads();
    int run = lds[t] - s + pre_s;
    if (base + 3 < TOT) {
        int4 o = make_int4(run, run + e0, run + e0 + e1, run + e0 + e1 + e2);
        *(int4*)(off_bin + base) = o;
    } else {
        int r = run;
        if (base + 0 < TOT) { off_bin[base + 0] = r; r += e0; }
        if (base + 1 < TOT) { off_bin[base + 1] = r; r += e1; }
        if (base + 2 < TOT) { off_bin[base + 2] = r; r += e2; }
        if (base + 3 < TOT) { off_bin[base + 3] = r; r += e3; }
    }
    if (bid == 0 && t == 0) off_bin[TOT] = 2 * NE;
}

// ---------------- MFMA bf16 GEMM body ----------------
__device__ __forceinline__ void gemm_dev(
    unsigned short* As, unsigned short* Bs,
    const void* __restrict__ Av, int aBf16, int M, int K, int lda,
    const unsigned short* __restrict__ Bn,
    void* __restrict__ C, int ldc, int mode,
    const float* __restrict__ sv, const float* __restrict__ tv,
    const float* __restrict__ node_embs, const int* __restrict__ flag,
    int m0, int n0)
{
    const int t = threadIdx.x;
    const int lane = t & 63, wave = t >> 6;
    const int wr = wave >> 1, wc = wave & 1;
    const int lrow = lane & 15, lkg = lane >> 4;

    f32x4 acc[2][2] = {};

    for (int kb = 0; kb < K; kb += 64) {
        if (aBf16) {
            const unsigned short* A = (const unsigned short*)Av;
#pragma unroll
            for (int it = 0; it < 2; ++it) {
                int idx = t + it * 256;
                int ko = idx & 7;
                int row = idx >> 3;
                int gm = m0 + row;
                uint4 a = make_uint4(0u, 0u, 0u, 0u);
                if (gm < M) a = *(const uint4*)(A + (size_t)gm * lda + kb + 8 * ko);
                *(uint4*)&As[row * 72 + 8 * ko] = a;
            }
        } else {
            const float* A = (const float*)Av;
#pragma unroll
            for (int it = 0; it < 4; ++it) {
                int idx = t + it * 256;
                int kq = idx & 15;
                int row = idx >> 4;
                int gm = m0 + row;
                float4 a = make_float4(0.f, 0.f, 0.f, 0.f);
                if (gm < M) a = *(const float4*)(A + (size_t)gm * lda + kb + 4 * kq);
                unsigned int p0 = (unsigned int)f2bf(a.x) | ((unsigned int)f2bf(a.y) << 16);
                unsigned int p1 = (unsigned int)f2bf(a.z) | ((unsigned int)f2bf(a.w) << 16);
                *(uint2*)&As[row * 72 + 4 * kq] = make_uint2(p0, p1);
            }
        }
#pragma unroll
        for (int it = 0; it < 2; ++it) {
            int idx = t + it * 256;
            int ko = idx & 7;
            int row = idx >> 3;
            uint4 b = *(const uint4*)(Bn + (size_t)(n0 + row) * K + kb + 8 * ko);
            *(uint4*)&Bs[row * 72 + 8 * ko] = b;
        }
        __syncthreads();
#pragma unroll
        for (int ks = 0; ks < 2; ++ks) {
            int k0 = ks * 32 + lkg * 8;
            bf16x8 af0 = *(const bf16x8*)&As[(wr * 32 + lrow) * 72 + k0];
            bf16x8 af1 = *(const bf16x8*)&As[(wr * 32 + 16 + lrow) * 72 + k0];
            bf16x8 bf0 = *(const bf16x8*)&Bs[(wc * 32 + lrow) * 72 + k0];
            bf16x8 bf1 = *(const bf16x8*)&Bs[(wc * 32 + 16 + lrow) * 72 + k0];
            acc[0][0] = __builtin_amdgcn_mfma_f32_16x16x32_bf16(af0, bf0, acc[0][0], 0, 0, 0);
            acc[0][1] = __builtin_amdgcn_mfma_f32_16x16x32_bf16(af0, bf1, acc[0][1], 0, 0, 0);
            acc[1][0] = __builtin_amdgcn_mfma_f32_16x16x32_bf16(af1, bf0, acc[1][0], 0, 0, 0);
            acc[1][1] = __builtin_amdgcn_mfma_f32_16x16x32_bf16(af1, bf1, acc[1][1], 0, 0, 0);
        }
        __syncthreads();
    }

#pragma unroll
    for (int m = 0; m < 2; ++m) {
#pragma unroll
        for (int r = 0; r < 4; ++r) {
            int gm = m0 + wr * 32 + m * 16 + lkg * 4 + r;
            if (gm >= M) continue;
#pragma unroll
            for (int n = 0; n < 2; ++n) {
                int gn = n0 + wc * 32 + n * 16 + lrow;
                float v = acc[m][n][r];
                if (mode == 0) {
                    ((unsigned short*)C)[(size_t)gm * ldc + gn] = f2bf(v);
                } else if (mode == 1) {
                    float val = (gn >= 192) ? tanhf(v + sv[gn - 192]) : v;
                    ((unsigned short*)C)[(size_t)gm * ldc + gn] = f2bf(val);
                } else {
                    float val = tanhf(v * sv[gn] + tv[gn]);
                    if (flag[0] == 0) val = node_embs[(size_t)gm * EMBD + gn];
                    ((float*)C)[(size_t)gm * EMBD + gn] = val;
                }
            }
        }
    }
}

__global__ __launch_bounds__(256) void gemm_mfma(
    const void* __restrict__ A, int aBf16, int M, int K, int lda,
    const unsigned short* __restrict__ Bn,
    void* __restrict__ C, int ldc, int mode,
    const float* __restrict__ sv, const float* __restrict__ tv,
    const float* __restrict__ node_embs, const int* __restrict__ flag)
{
    __shared__ unsigned short As[64 * 72];
    __shared__ unsigned short Bs[64 * 72];
    gemm_dev(As, Bs, A, aBf16, M, K, lda, Bn, C, ldc, mode, sv, tv, node_embs, flag,
             blockIdx.x * 64, blockIdx.y * 64);
}

// ---------------- K5: scatter (atomic-free, nt stores, FIRST) || E1-GEMM || C1-GEMM ----------------
// record: bits 0-14 = other node, 15-23 = evid, 31 = dir (0=IN, 1=OUT)
__global__ __launch_bounds__(256) void k_mega(
    const float* __restrict__ node_embs, const float* __restrict__ edge_embs,
    const unsigned short* __restrict__ Bn1,
    unsigned short* __restrict__ C1b, unsigned short* __restrict__ E1b,
    const float* __restrict__ br1,
    const int* __restrict__ src, const int* __restrict__ dst,
    const int* __restrict__ evid, const unsigned* __restrict__ rank2,
    const int* __restrict__ offc, unsigned* __restrict__ R)
{
    __shared__ unsigned short As[64 * 72];
    __shared__ unsigned short Bs[64 * 72];
    int bid = blockIdx.x;
    if (bid < NBLK_HIST) {
        int e = bid * 256 + threadIdx.x;
        if (e < NE) {
            int s = src[e], d = dst[e];
            unsigned rv = (unsigned)evid[e] << 15;
            unsigned rk = rank2[e];
            __builtin_nontemporal_store((unsigned)s | rv,
                                        &R[offc[2 * d] + (rk & 0xFFFFu)]);
            __builtin_nontemporal_store((unsigned)d | rv | 0x80000000u,
                                        &R[offc[2 * s + 1] + (rk >> 16)]);
        }
        return;
    }
    int b2 = bid - NBLK_HIST;
    if (b2 < NBLK_GE1) {
        gemm_dev(As, Bs, edge_embs, 0, NR, 256, 256, Bn1, E1b, 256, 1,
                 br1, nullptr, nullptr, nullptr,
                 (b2 % 8) * 64, (b2 / 8) * 64);
    } else {
        int b3 = b2 - NBLK_GE1;
        gemm_dev(As, Bs, node_embs, 0, NN, 256, 256, Bn1, C1b, 192, 0,
                 nullptr, nullptr, nullptr, nullptr,
                 (b3 % 313) * 64, (b3 / 313) * 64);
    }
}

// ---------------- merged-direction CSR gather (one range per node, dir in bit 31) ----------------

__device__ __forceinline__ void gather_quad_m(
    const unsigned* __restrict__ R, int r0, int r1, int g, int q,
    const unsigned short* __restrict__ TAB, int ldt, int toff0, int toff1,
    const unsigned short* __restrict__ ETAB, int eoff0, int eoff1,
    float4& accO, float4& accI)
{
    int lane = g * 16 + q;
    int cnt = r1 - r0;
    for (int base = 0; base < cnt; base += 64) {
        int rem = cnt - base; if (rem > 64) rem = 64;
        unsigned rec = 0u;
        if (lane < rem) rec = __builtin_nontemporal_load(&R[r0 + base + lane]);
        int i = 0;
        for (; 4 * i + 15 < rem; i += 4) {
            unsigned r4[4];
            r4[0] = __shfl(rec, 4 * i + g, 64);
            r4[1] = __shfl(rec, 4 * i + 4 + g, 64);
            r4[2] = __shfl(rec, 4 * i + 8 + g, 64);
            r4[3] = __shfl(rec, 4 * i + 12 + g, 64);
            uint2 ua[4], ue[4];
#pragma unroll
            for (int u = 0; u < 4; ++u) {
                unsigned rv = r4[u];
                int dir = (int)(rv >> 31);
                ua[u] = *(const uint2*)(TAB + (size_t)(rv & 0x7FFFu) * ldt +
                                        (dir ? toff1 : toff0) + 4 * q);
                ue[u] = *(const uint2*)(ETAB + (size_t)((rv >> 15) & 0x1FFu) * 256 +
                                        (dir ? eoff1 : eoff0) + 4 * q);
            }
#pragma unroll
            for (int u = 0; u < 4; ++u) {
                float4 a = bf4tof4(ua[u]), e = bf4tof4(ue[u]);
                // r4[u] is a shfl broadcast -> wave-uniform branch, no divergence
                if (r4[u] >> 31) {
                    accI.x += a.x - e.x; accI.y += a.y - e.y;
                    accI.z += a.z - e.z; accI.w += a.w - e.w;
                } else {
                    accO.x += a.x - e.x; accO.y += a.y - e.y;
                    accO.z += a.z - e.z; accO.w += a.w - e.w;
                }
            }
        }
        for (; 4 * i < rem; ++i) {
            int idx = 4 * i + g;
            unsigned rr = __shfl(rec, idx < rem ? idx : 0, 64);
            if (idx < rem) {
                int dir = (int)(rr >> 31);
                uint2 ua = *(const uint2*)(TAB + (size_t)(rr & 0x7FFFu) * ldt +
                                           (dir ? toff1 : toff0) + 4 * q);
                uint2 ue = *(const uint2*)(ETAB + (size_t)((rr >> 15) & 0x1FFu) * 256 +
                                           (dir ? eoff1 : eoff0) + 4 * q);
                float4 a = bf4tof4(ua), e = bf4tof4(ue);
                if (dir) {
                    accI.x += a.x - e.x; accI.y += a.y - e.y;
                    accI.z += a.z - e.z; accI.w += a.w - e.w;
                } else {
                    accO.x += a.x - e.x; accO.y += a.y - e.y;
                    accO.z += a.z - e.z; accO.w += a.w - e.w;
                }
            }
        }
    }
}

__device__ __forceinline__ void xreduce(float4& v)
{
    v.x += __shfl_xor(v.x, 16, 64); v.y += __shfl_xor(v.y, 16, 64);
    v.z += __shfl_xor(v.z, 16, 64); v.w += __shfl_xor(v.w, 16, 64);
    v.x += __shfl_xor(v.x, 32, 64); v.y += __shfl_xor(v.y, 32, 64);
    v.z += __shfl_xor(v.z, 32, 64); v.w += __shfl_xor(v.w, 32, 64);
}

__device__ __forceinline__ uint2 packbf4(float4 o)
{
    return make_uint2((unsigned)f2bf(o.x) | ((unsigned)f2bf(o.y) << 16),
                      (unsigned)f2bf(o.z) | ((unsigned)f2bf(o.w) << 16));
}

// layer 1 fused with combine -> A2b[.,128:192) bf16
__global__ __launch_bounds__(256) void k_gather1(
    const int* __restrict__ offc, const unsigned* __restrict__ R,
    const unsigned short* __restrict__ C1b, const unsigned short* __restrict__ E1b,
    const float* __restrict__ s1, const float* __restrict__ t1,
    unsigned short* __restrict__ A2b)
{
    int n = blockIdx.x * 4 + (threadIdx.x >> 6);
    if (n >= NN) return;
    int lane = threadIdx.x & 63, g = lane >> 4, q = lane & 15;
    int b0 = offc[2 * n], bm = offc[2 * n + 1], b1 = offc[2 * n + 2];
    float di = 1.f / fmaxf((float)(bm - b0), 1.f);
    float dh = 1.f / fmaxf((float)(b1 - bm), 1.f);
    float4 accO = make_float4(0.f, 0.f, 0.f, 0.f);
    float4 accI = make_float4(0.f, 0.f, 0.f, 0.f);
    gather_quad_m(R, b0, b1, g, q, C1b, 192, 0, 64, E1b, 0, 64, accO, accI);
    xreduce(accO);
    xreduce(accI);
    if (g == 0) {
        float4 hs = bf4tof4(*(const uint2*)(C1b + (size_t)n * 192 + 128 + 4 * q));
        float4 sv = *(const float4*)(s1 + 4 * q);
        float4 tv = *(const float4*)(t1 + 4 * q);
        float4 o;
        o.x = tanhf((accO.x * di + accI.x * dh + hs.x) * sv.x + tv.x);
        o.y = tanhf((accO.y * di + accI.y * dh + hs.y) * sv.y + tv.y);
        o.z = tanhf((accO.z * di + accI.z * dh + hs.z) * sv.z + tv.z);
        o.w = tanhf((accO.w * di + accI.w * dh + hs.w) * sv.w + tv.w);
        *(uint2*)(A2b + (size_t)n * 192 + 128 + 4 * q) = packbf4(o);
    }
}

// layer 2 -> A2b cols [0,128)  (both dirs read the same table offsets)
__global__ __launch_bounds__(256) void k_gather2(
    const int* __restrict__ offc, const unsigned* __restrict__ R,
    const unsigned short* __restrict__ A2r, const unsigned short* __restrict__ E1b,
    unsigned short* __restrict__ A2w)
{
    int n = blockIdx.x * 4 + (threadIdx.x >> 6);
    if (n >= NN) return;
    int lane = threadIdx.x & 63, g = lane >> 4, q = lane & 15;
    int b0 = offc[2 * n], bm = offc[2 * n + 1], b1 = offc[2 * n + 2];
    float di = 1.f / fmaxf((float)(bm - b0), 1.f);
    float dh = 1.f / fmaxf((float)(b1 - bm), 1.f);
    float4 accO = make_float4(0.f, 0.f, 0.f, 0.f);
    float4 accI = make_float4(0.f, 0.f, 0.f, 0.f);
    gather_quad_m(R, b0, b1, g, q, A2r, 192, 128, 128, E1b, 192, 192, accO, accI);
    xreduce(accO);
    xreduce(accI);
    if (g == 0) {
        float4 o0, o1;
        o0.x = accO.x * di; o0.y = accO.y * di; o0.z = accO.z * di; o0.w = accO.w * di;
        o1.x = accI.x * dh; o1.y = accI.y * dh; o1.z = accI.z * dh; o1.w = accI.w * dh;
        *(uint2*)(A2w + (size_t)n * 192 + 4 * q) = packbf4(o0);
        *(uint2*)(A2w + (size_t)n * 192 + 64 + 4 * q) = packbf4(o1);
    }
}

// ---------------- scoring (tvec fused) ----------------
__global__ __launch_bounds__(256) void k_score(
    const float* __restrict__ hn, const float* __restrict__ rels,
    const int* __restrict__ hids, const int* __restrict__ tids,
    const int* __restrict__ is_head, float* __restrict__ score)
{
    int p = blockIdx.x * 4 + (threadIdx.x >> 6);
    if (p >= BQ * (NN / BQ)) return;
    int l = threadIdx.x & 63;
    int b = p / (NN / BQ);
    int j = p - b * (NN / BQ);
    int idx = (b * NN + 32 * j) / BQ;   // faithful repeat_interleave indexing
    int ih = is_head[0];
    int nid = ih ? tids[b] : hids[b];
    float ssum = 0.f;
#pragma unroll
    for (int q = 0; q < 4; ++q) {
        float r = rels[b * 256 + l + 64 * q];
        float hv = hn[(size_t)nid * 256 + l + 64 * q];
        float tv = ih ? (hv - r) : (hv + r);
        float df = hn[(size_t)idx * 256 + l + 64 * q] - tv;
        ssum = fmaf(df, df, ssum);
    }
#pragma unroll
    for (int off = 32; off >= 1; off >>= 1) ssum += __shfl_xor(ssum, off, 64);
    float dist = sqrtf(ssum);
    float sc = 1.f / (1.f + expf(dist - 12.f));
    if (l < 32) score[(size_t)b * NN + 32 * j + l] = sc;
}

// ---------------- launch ----------------
extern "C" void kernel_launch(void* const* d_in, const int* in_sizes, int n_in,
                              void* d_out, int out_size, void* d_ws, size_t ws_size,
                              hipStream_t stream)
{
    const float* node_embs = (const float*)d_in[0];
    const float* edge_embs = (const float*)d_in[1];
    const float* W_O1 = (const float*)d_in[2];  const float* b_O1 = (const float*)d_in[3];
    const float* W_I1 = (const float*)d_in[4];  const float* b_I1 = (const float*)d_in[5];
    const float* W_S1 = (const float*)d_in[6];  const float* b_S1 = (const float*)d_in[7];
    const float* bn1_g = (const float*)d_in[8]; const float* bn1_b = (const float*)d_in[9];
    const float* bn1_m = (const float*)d_in[10];const float* bn1_v = (const float*)d_in[11];
    const float* Wr1 = (const float*)d_in[12];  const float* br1 = (const float*)d_in[13];
    const float* W_O2 = (const float*)d_in[14]; const float* b_O2 = (const float*)d_in[15];
    const float* W_I2 = (const float*)d_in[16]; const float* b_I2 = (const float*)d_in[17];
    const float* W_S2 = (const float*)d_in[18]; const float* b_S2 = (const float*)d_in[19];
    const float* bn2_g = (const float*)d_in[20];const float* bn2_b = (const float*)d_in[21];
    const float* bn2_m = (const float*)d_in[22];const float* bn2_v = (const float*)d_in[23];
    const float* Wr2 = (const float*)d_in[24];  const float* br2 = (const float*)d_in[25];
    const int* src = (const int*)d_in[26];
    const int* dst = (const int*)d_in[27];
    const int* evid = (const int*)d_in[28];
    const int* hids = (const int*)d_in[29];
    const int* rids = (const int*)d_in[30];
    const int* tids = (const int*)d_in[31];
    const int* upd = (const int*)d_in[32];
    const int* ihead = (const int*)d_in[33];

    unsigned short* C1b = (unsigned short*)d_ws;           // 20000*192
    unsigned short* A2b = C1b + 3840000;                   // 20000*192
    unsigned short* E1b = A2b + 3840000;                   // 500*256
    unsigned short* Bn1 = E1b + 128000;                    // 256*256
    unsigned short* Bn2 = Bn1 + 65536;                     // 256*192

    float* s1   = (float*)(Bn2 + 49152);   // 64
    float* t1   = s1 + 64;                 // 64
    float* s2   = t1 + 64;                 // 256
    float* t2   = s2 + 256;                // 256
    float* rels = t2 + 256;                // 32*256

    unsigned* R     = (unsigned*)(rels + 8192);  // 2*NE packed records
    unsigned* rank2 = R + 2 * NE;                // NE (rank_in | rank_out<<16)
    int* cnt    = (int*)(rank2 + NE);      // TOT   (memset)
    int* flag   = cnt + TOT;               // 1     (memset, contiguous)
    int* off_bin= flag + 1;                // TOT+1
    int* bsum   = off_bin + TOT + 1;       // NB

    float* hn    = (float*)d_out;                       // 20000*256
    float* score = hn + (size_t)NN * EMBD;              // 32*20000

    hipMemsetAsync(cnt, 0, (size_t)(TOT + 1) * 4, stream);

    // K1: hist(+ranks) || weight-pack || params || rels-MLP
    k_prep<<<NBLK_K1, 256, 0, stream>>>(
        src, dst, cnt, rank2,
        W_O1, W_I1, W_S1, Wr1, W_O2, W_I2, W_S2, Bn1, Bn2,
        b_O1, b_I1, b_S1, bn1_g, bn1_b, bn1_m, bn1_v,
        b_O2, b_I2, b_S2, bn2_g, bn2_b, bn2_m, bn2_v,
        s1, t1, s2, t2,
        edge_embs, br1, br2, Wr2, rids, rels);

    // fused scan (1 kernel)
    k_scan<<<NB, 256, 0, stream>>>(cnt, off_bin, bsum, flag);

    // K5: scatter-first (nt stores) || E1-GEMM || C1-GEMM
    k_mega<<<NBLK_MEGA, 256, 0, stream>>>(node_embs, edge_embs, Bn1,
                                          C1b, E1b, br1, src, dst, evid, rank2, off_bin, R);

    // layer-1 aggregation + combine (writes h1 into A2b cols [128,192))
    k_gather1<<<NN / 4, 256, 0, stream>>>(off_bin, R, C1b, E1b, s1, t1, A2b);
    // layer-2 aggregation (writes A2b cols [0,128))
    k_gather2<<<NN / 4, 256, 0, stream>>>(off_bin, R, A2b, E1b, A2b);

    // hn = tanh((A2b @ Bn2^T) * s2 + t2)  (or node_embs if !upd)
    gemm_mfma<<<dim3(313, 4), 256, 0, stream>>>(A2b, 1, NN, 192, 192, Bn2,
                                                hn, 256, 2, s2, t2, node_embs, upd);

    // scoring (tvec fused)
    k_score<<<(BQ * (NN / BQ)) / 4, 256, 0, stream>>>(hn, rels, hids, tids, ihead, score);
}